// Round 6
// baseline (22027.122 us; speedup 1.0000x reference)
//
#include <hip/hip_runtime.h>

// GraphMemoryNetwork on MI355X — all reference tensors are float32.
// 7 small GEMMs (bf16 MFMA, f32 accum) + 3 sequential LSTM scans of T=8192
// steps. Scan v4: 1024 threads (16 waves, 4/SIMD -> 128-VGPR budget, AGPR
// offload structurally pointless). 4-lane cluster per hidden unit; lane s
// owns gate-row s and K-slice dwords s*16..s*16+15 (64 weight dwords/thread).
// XOR-slot butterfly (2 rounds) reduces partial dots; quad-perm shuffles
// combine gates; c/h chain on lane s==1. h broadcast via LDS i8, double
// buffered; ONE raw s_barrier per step (lgkmcnt-only wait).

typedef __attribute__((ext_vector_type(8))) short short8;   // 8 bf16 (4 VGPRs)
typedef __attribute__((ext_vector_type(4))) float f32x4;

#define LOG2E 1.44269504088896340736f

__device__ __forceinline__ float fast_sigmoid(float x) {
  float e = __builtin_amdgcn_exp2f(-x * LOG2E);
  return __builtin_amdgcn_rcpf(1.0f + e);
}
__device__ __forceinline__ float fast_tanh(float x) {
  float e = __builtin_amdgcn_exp2f(x * (2.0f * LOG2E));   // e^{2x}
  return 1.0f - 2.0f * __builtin_amdgcn_rcpf(e + 1.0f);
}

__device__ __forceinline__ unsigned short f2bf(float x) {  // RNE, no NaN inputs
  unsigned int u = __float_as_uint(x);
  u += 0x7FFFu + ((u >> 16) & 1u);
  return (unsigned short)(u >> 16);
}

#if __has_builtin(__builtin_amdgcn_sdot4)
#define SDOT4(a, b, c) __builtin_amdgcn_sdot4((a), (b), (c), false)
#else
__device__ __forceinline__ int sdot4_sw(int a, int b, int c) {
  c += ((a << 24) >> 24) * ((b << 24) >> 24);
  c += ((a << 16) >> 24) * ((b << 16) >> 24);
  c += ((a << 8) >> 24) * ((b << 8) >> 24);
  c += (a >> 24) * (b >> 24);
  return c;
}
#define SDOT4(a, b, c) sdot4_sw((a), (b), (c))
#endif

// ---------------------------------------------------------------------------
// GEMM: C[M,N] = A[M,K] * W[N,K]^T + bias0 + bias1.  A,W bf16 row-major
// (ushort). biases f32. 128x128 tile, BK=64, 4 waves (2x2), 16x16x32 bf16
// MFMA, reg-staged LDS.  K % 64 == 0.
// ---------------------------------------------------------------------------
__global__ __launch_bounds__(256) void gemm_bt(
    const unsigned short* __restrict__ A, int lda,
    const unsigned short* __restrict__ W, int ldw,
    const float* __restrict__ bias0,
    const float* __restrict__ bias1,
    void* __restrict__ C, int ldc, int c_f32, int K)
{
  __shared__ unsigned short As[128 * 64];
  __shared__ unsigned short Bs[128 * 64];
  const int tid = threadIdx.x;
  const int lane = tid & 63;
  const int w = tid >> 6;
  const int wm = w >> 1, wn = w & 1;
  const int bm = blockIdx.y * 128, bn = blockIdx.x * 128;

  f32x4 acc[4][4];
#pragma unroll
  for (int m = 0; m < 4; ++m)
#pragma unroll
    for (int n = 0; n < 4; ++n)
      acc[m][n] = (f32x4){0.f, 0.f, 0.f, 0.f};

  for (int k0 = 0; k0 < K; k0 += 64) {
    uint4 va[4], vb[4];
#pragma unroll
    for (int i = 0; i < 4; ++i) {
      int c = i * 256 + tid;                  // 16B chunk id within 128x64 tile
      va[i] = *(const uint4*)(A + (size_t)(bm + (c >> 3)) * lda + k0 + (c & 7) * 8);
      vb[i] = *(const uint4*)(W + (size_t)(bn + (c >> 3)) * ldw + k0 + (c & 7) * 8);
    }
    __syncthreads();                          // prev-iter LDS reads done
#pragma unroll
    for (int i = 0; i < 4; ++i) {
      int c = i * 256 + tid;
      *(uint4*)&As[c * 8] = va[i];
      *(uint4*)&Bs[c * 8] = vb[i];
    }
    __syncthreads();                          // tile ready
#pragma unroll
    for (int ks = 0; ks < 2; ++ks) {
      short8 a[4], b[4];
#pragma unroll
      for (int m = 0; m < 4; ++m)
        a[m] = *(const short8*)&As[(wm * 64 + m * 16 + (lane & 15)) * 64 + ks * 32 + (lane >> 4) * 8];
#pragma unroll
      for (int n = 0; n < 4; ++n)
        b[n] = *(const short8*)&Bs[(wn * 64 + n * 16 + (lane & 15)) * 64 + ks * 32 + (lane >> 4) * 8];
#pragma unroll
      for (int m = 0; m < 4; ++m)
#pragma unroll
        for (int n = 0; n < 4; ++n)
          acc[m][n] = __builtin_amdgcn_mfma_f32_16x16x32_bf16(a[m], b[n], acc[m][n], 0, 0, 0);
    }
  }

  // epilogue: C/D layout col=lane&15, row=(lane>>4)*4+reg
#pragma unroll
  for (int n = 0; n < 4; ++n) {
    int col = bn + wn * 64 + n * 16 + (lane & 15);
    float bsum = 0.f;
    if (bias0) bsum += bias0[col];
    if (bias1) bsum += bias1[col];
#pragma unroll
    for (int m = 0; m < 4; ++m) {
      int rbase = bm + wm * 64 + m * 16 + ((lane >> 4) * 4);
#pragma unroll
      for (int q = 0; q < 4; ++q) {
        float v = acc[m][n][q] + bsum;
        if (c_f32)
          ((float*)C)[(size_t)(rbase + q) * ldc + col] = v;
        else
          ((unsigned short*)C)[(size_t)(rbase + q) * ldc + col] = f2bf(v);
      }
    }
  }
}

// ---------------------------------------------------------------------------
// f32 -> bf16 conversions
// ---------------------------------------------------------------------------
__global__ void f2bf_flat(const float* __restrict__ src,
                          unsigned short* __restrict__ dst, int n4)
{
  int gid = blockIdx.x * 256 + threadIdx.x;
  if (gid >= n4) return;
  f32x4 v = ((const f32x4*)src)[gid];
  ushort4 o;
  o.x = f2bf(v.x); o.y = f2bf(v.y); o.z = f2bf(v.z); o.w = f2bf(v.w);
  ((ushort4*)dst)[gid] = o;
}

// copy f32 [rows, width] (contig) into bf16 [rows, dstLd] column block
__global__ void f2bf_strided(const float* __restrict__ src,
                             unsigned short* __restrict__ dst, int dstLd,
                             int chunkShift, int total)   // chunks of 4 elems
{
  int gid = blockIdx.x * 256 + threadIdx.x;
  if (gid >= total) return;
  int row = gid >> chunkShift;
  int ch = gid & ((1 << chunkShift) - 1);
  f32x4 v = ((const f32x4*)src)[(size_t)gid];
  ushort4 o;
  o.x = f2bf(v.x); o.y = f2bf(v.y); o.z = f2bf(v.z); o.w = f2bf(v.w);
  *(ushort4*)(dst + (size_t)row * dstLd + ch * 4) = o;
}

// ---------------------------------------------------------------------------
// Quantize LSTM recurrent weights [nrows x 256] f32 -> i8, TRANSPOSED output
// wqT[k*nrows + row] (k = packed-dword index 0..63), + per-row scale (max/127).
// One wave per row.
// ---------------------------------------------------------------------------
__global__ void quant_rows(const float* __restrict__ Wsrc,
                           int* __restrict__ wqT, float* __restrict__ scales,
                           int nrows)
{
  int row = blockIdx.x * 4 + (threadIdx.x >> 6);
  if (row >= nrows) return;
  int lane = threadIdx.x & 63;
  float v[4];
  float mx = 0.f;
#pragma unroll
  for (int i = 0; i < 4; ++i) {
    v[i] = Wsrc[(size_t)row * 256 + lane * 4 + i];
    mx = fmaxf(mx, fabsf(v[i]));
  }
#pragma unroll
  for (int d = 32; d >= 1; d >>= 1) mx = fmaxf(mx, __shfl_xor(mx, d));
  float inv = (mx > 0.f) ? 127.f / mx : 0.f;
  int packed = 0;
#pragma unroll
  for (int i = 0; i < 4; ++i) {
    int q = __float2int_rn(v[i] * inv);
    q = max(-127, min(127, q));
    packed |= (q & 0xFF) << (8 * i);
  }
  wqT[(size_t)lane * nrows + row] = packed;
  if (lane == 0) scales[row] = mx / 127.f;
}

// ---------------------------------------------------------------------------
// Sequential LSTM scan v4. T steps, H=256 (1024 gate rows), one 1024-thread
// workgroup (16 waves, 4/SIMD, <=128 VGPR budget -> weights arch-resident).
// Cluster of 4 lanes = 1 hidden unit (unit = tid>>2); lane s = gate s
// (PyTorch order i,f,g,o). Lane s holds K-slice dwords s*16..s*16+15 for all
// 4 gate rows of its unit, with XOR-slot assignment: slot j <-> gate (s^j).
// Butterfly (xor 1,2) reduces slices; slot0 = own gate's full dot.
// ---------------------------------------------------------------------------
__global__ __launch_bounds__(1024)
void lstm_scan(
    const float* __restrict__ xg,     // [T][1024]  (includes bih+bhh)
    const int* __restrict__ wqT,      // [64][1024] transposed packed i8
    const float* __restrict__ wsc,    // [1024] row scales (mx/127)
    unsigned short* __restrict__ hs,  // [T][ldh] bf16 output
    int T, int ldh)
{
  const int tid  = threadIdx.x;
  const int unit = tid >> 2;          // 0..255
  const int s    = tid & 3;           // gate lane
  const int row  = s * 256 + unit;    // this lane's own gate row

  // weights: w[j][kk] = wqT[(s*16+kk)*1024 + (s^j)*256 + unit]
  int w[4][16];
#pragma unroll
  for (int j = 0; j < 4; ++j)
#pragma unroll
    for (int kk = 0; kk < 16; ++kk)
      w[j][kk] = wqT[(s * 16 + kk) * 1024 + ((s ^ j) << 8) + unit];
  // pin to arch-VGPR class (zero instructions)
#pragma unroll
  for (int j = 0; j < 4; ++j)
#pragma unroll
    for (int kk = 0; kk < 16; ++kk)
      asm("" : "+v"(w[j][kk]));

  const float sc = wsc[row] * (1.f / 127.f);
  // activation: gate g (s==2) -> tanh(x)=2*sig(2x)-1 ; else sigmoid
  const float A2 = (s == 2) ? 2.f : 1.f;
  const float D2 = (s == 2) ? -1.f : 0.f;

  __shared__ __align__(16) int hq[2][64];   // h as i8 (scale 127), dbuf
  if (tid < 64) { hq[0][tid] = 0; hq[1][tid] = 0; }
  float c = 0.f;                            // cell state (lane s==1 only)

  // depth-2 xg pipeline; uniform cursor + per-thread row offset
  const float* xp = xg;
  float xA = xp[row];
  float xB = xp[1024 + row];
  xp += 2048;                               // cursor at t+2

  __syncthreads();

#define STEP(T_, HB, HBN, X)                                              \
  {                                                                       \
    float xcur = X;                                                       \
    X = xp[row];                 /* prefetch t+2 (overrun is benign) */   \
    xp += 1024;                                                           \
    int a0 = 0, a1 = 0, a2 = 0, a3 = 0;                                   \
    _Pragma("unroll")                                                     \
    for (int kt = 0; kt < 4; ++kt) {                                      \
      int4 hc = ((const int4*)(HB))[s * 4 + kt];                          \
      a0 = SDOT4(w[0][kt * 4 + 0], hc.x, a0);                             \
      a1 = SDOT4(w[1][kt * 4 + 0], hc.x, a1);                             \
      a2 = SDOT4(w[2][kt * 4 + 0], hc.x, a2);                             \
      a3 = SDOT4(w[3][kt * 4 + 0], hc.x, a3);                             \
      a0 = SDOT4(w[0][kt * 4 + 1], hc.y, a0);                             \
      a1 = SDOT4(w[1][kt * 4 + 1], hc.y, a1);                             \
      a2 = SDOT4(w[2][kt * 4 + 1], hc.y, a2);                             \
      a3 = SDOT4(w[3][kt * 4 + 1], hc.y, a3);                             \
      a0 = SDOT4(w[0][kt * 4 + 2], hc.z, a0);                             \
      a1 = SDOT4(w[1][kt * 4 + 2], hc.z, a1);                             \
      a2 = SDOT4(w[2][kt * 4 + 2], hc.z, a2);                             \
      a3 = SDOT4(w[3][kt * 4 + 2], hc.z, a3);                             \
      a0 = SDOT4(w[0][kt * 4 + 3], hc.w, a0);                             \
      a1 = SDOT4(w[1][kt * 4 + 3], hc.w, a1);                             \
      a2 = SDOT4(w[2][kt * 4 + 3], hc.w, a2);                             \
      a3 = SDOT4(w[3][kt * 4 + 3], hc.w, a3);                             \
    }                                                                     \
    /* XOR-slot butterfly: acc[j] += shfl_xor(acc[j^d], d), d=1,2 */      \
    {                                                                     \
      int v0 = __shfl_xor(a1, 1), v1 = __shfl_xor(a0, 1);                 \
      int v2 = __shfl_xor(a3, 1), v3 = __shfl_xor(a2, 1);                 \
      a0 += v0; a1 += v1; a2 += v2; a3 += v3;                             \
      v0 = __shfl_xor(a2, 2); v1 = __shfl_xor(a3, 2);                     \
      a0 += v0; a1 += v1;                                                 \
    }                                                                     \
    float p = fmaf((float)a0, sc, xcur);      /* own gate preact */       \
    float act = A2 * fast_sigmoid(A2 * p) + D2;                           \
    float cross = __shfl_xor(act, 2);         /* lane0:g~ lane1:o */      \
    float u = act * cross;                    /* lane0: i*g~ */           \
    float un = __shfl_xor(u, 1);              /* lane1 <- i*g~ */         \
    if (s == 1) {                             /* act=f, cross=o */        \
      c = fmaf(act, c, un);                                               \
      float h = cross * fast_tanh(c);                                     \
      hs[(size_t)(T_) * ldh + unit] = f2bf(h);                            \
      int q = __float2int_rn(h * 127.f);                                  \
      q = max(-127, min(127, q));                                         \
      ((char*)(HBN))[unit] = (char)q;                                     \
    }                                                                     \
    asm volatile("s_waitcnt lgkmcnt(0)" ::: "memory");                    \
    __builtin_amdgcn_s_barrier();                                         \
    asm volatile("" ::: "memory");                                        \
  }

  for (int t = 0; t < T; t += 2) {
    STEP(t,     hq[0], hq[1], xA);
    STEP(t + 1, hq[1], hq[0], xB);
  }
#undef STEP
}

// ---------------------------------------------------------------------------
// pair[n] = [nodes[e0[n]] | nodes[e1[n]]]  (bf16, 16B chunks)
// ---------------------------------------------------------------------------
__global__ void gather_pair(const unsigned short* __restrict__ nodes,
                            const int* __restrict__ edges,
                            unsigned short* __restrict__ pair)
{
  int gid = blockIdx.x * 256 + threadIdx.x;   // over 8192*64 chunks
  int row = gid >> 6;
  int ch = gid & 63;
  int side = ch >> 5;
  int k = ch & 31;
  int src = edges[row * 2 + side];
  uint4 v = ((const uint4*)(nodes + (size_t)src * 256))[k];
  ((uint4*)(pair + (size_t)row * 512))[ch] = v;
}

// ---------------------------------------------------------------------------
extern "C" void kernel_launch(void* const* d_in, const int* in_sizes, int n_in,
                              void* d_out, int out_size, void* d_ws, size_t ws_size,
                              hipStream_t stream)
{
  const float* inputs   = (const float*)d_in[0];
  const int*   edges    = (const int*)d_in[1];
  const float* memory   = (const float*)d_in[2];
  const float* Wi       = (const float*)d_in[3];
  const float* bi       = (const float*)d_in[4];
  const float* Wo       = (const float*)d_in[5];
  const float* bo       = (const float*)d_in[6];
  const float* edge_W   = (const float*)d_in[7];
  const float* edge_b   = (const float*)d_in[8];
  const float* node_Wih = (const float*)d_in[9];
  const float* node_Whh = (const float*)d_in[10];
  const float* node_bih = (const float*)d_in[11];
  const float* node_bhh = (const float*)d_in[12];
  const float* Wm       = (const float*)d_in[13];
  const float* bm       = (const float*)d_in[14];
  const float* cWih     = (const float*)d_in[15];
  const float* cWhh     = (const float*)d_in[16];
  const float* cbih     = (const float*)d_in[17];
  const float* cbhh     = (const float*)d_in[18];

  char* ws = (char*)d_ws;
  float*          xgbuf  = (float*)(ws + 0);                    // [8192,1024] f32
  unsigned short* Xbf    = (unsigned short*)(ws + 33554432);    // [8192,512]  inputs|edge_h
  unsigned short* Xc     = (unsigned short*)(ws + 41943040);    // [8192,640]  inputs|nodes2|memory
  unsigned short* nodes0 = (unsigned short*)(ws + 52428800);    // [8192,256]
  unsigned short* nodesA = (unsigned short*)(ws + 56623104);    // [8192,256]
  unsigned short* PAIR   = (unsigned short*)(ws + 60817408);    // [8192,512]
  unsigned short* hsC    = (unsigned short*)(ws + 69206016);    // [8192,256]
  unsigned short* WiB    = (unsigned short*)(ws + 73400320);    // 131072 B
  unsigned short* WoB    = (unsigned short*)(ws + 73531392);    // 131072 B
  unsigned short* eWB    = (unsigned short*)(ws + 73662464);    // 524288 B
  unsigned short* nWihB  = (unsigned short*)(ws + 74186752);    // 2097152 B
  unsigned short* WmB    = (unsigned short*)(ws + 76283904);    // 65536 B
  unsigned short* cWihB  = (unsigned short*)(ws + 76349440);    // 1310720 B
  int*            wqN0   = (int*)(ws + 77660160);               // [64][1024]
  int*            wqN1   = (int*)(ws + 77922304);               // [64][1024]
  int*            wqC    = (int*)(ws + 78184448);               // [64][1024]
  float*          scN0   = (float*)(ws + 78446592);             // [1024]
  float*          scN1   = (float*)(ws + 78450688);             // [1024]
  float*          scC    = (float*)(ws + 78454784);             // [1024]

  float* out0 = (float*)d_out;                // out     [8192,256] f32
  float* out1 = out0 + 8192 * 256;            // memvec  [8192,128] f32

  // --- prep: weight conversions + recurrent-weight quantization ---
  quant_rows<<<256, 256, 0, stream>>>(node_Whh, wqN0, scN0, 1024);
  quant_rows<<<256, 256, 0, stream>>>(node_Whh + 1024 * 256, wqN1, scN1, 1024);
  quant_rows<<<256, 256, 0, stream>>>(cWhh, wqC, scC, 1024);
  f2bf_flat<<<64, 256, 0, stream>>>(Wi, WiB, 16384);
  f2bf_flat<<<64, 256, 0, stream>>>(Wo, WoB, 16384);
  f2bf_flat<<<256, 256, 0, stream>>>(edge_W, eWB, 65536);
  f2bf_flat<<<1024, 256, 0, stream>>>(node_Wih, nWihB, 262144);
  f2bf_flat<<<32, 256, 0, stream>>>(Wm, WmB, 8192);
  f2bf_flat<<<640, 256, 0, stream>>>(cWih, cWihB, 163840);

  // --- static column blocks (inputs, memory) as bf16 ---
  f2bf_strided<<<2048, 256, 0, stream>>>(inputs, Xbf, 512, 6, 8192 * 64);
  f2bf_strided<<<2048, 256, 0, stream>>>(inputs, Xc, 640, 6, 8192 * 64);
  f2bf_strided<<<1024, 256, 0, stream>>>(memory, Xc + 512, 640, 5, 8192 * 32);

  // --- input layer: nodes0 = inputs @ Wi^T + bi ---
  gemm_bt<<<dim3(2, 64), 256, 0, stream>>>(Xbf, 512, WiB, 256, bi, nullptr,
                                           nodes0, 256, 0, 256);

  // --- relation r = 0 ---
  gather_pair<<<2048, 256, 0, stream>>>(nodes0, edges, PAIR);
  gemm_bt<<<dim3(2, 64), 256, 0, stream>>>(PAIR, 512, eWB, 512, edge_b, nullptr,
                                           Xbf + 256, 512, 0, 512);
  gemm_bt<<<dim3(8, 64), 256, 0, stream>>>(Xbf, 512, nWihB, 512, node_bih, node_bhh,
                                           xgbuf, 1024, 1, 512);
  lstm_scan<<<1, 1024, 0, stream>>>(xgbuf, wqN0, scN0, nodesA, 8192, 256);

  // --- relation r = 1 (LSTM writes straight into Xc[:,256:512]) ---
  gather_pair<<<2048, 256, 0, stream>>>(nodesA, edges, PAIR);
  gemm_bt<<<dim3(2, 64), 256, 0, stream>>>(PAIR, 512, eWB + 256 * 512, 512,
                                           edge_b + 256, nullptr, Xbf + 256, 512, 0, 512);
  gemm_bt<<<dim3(8, 64), 256, 0, stream>>>(Xbf, 512, nWihB + 1024 * 512, 512,
                                           node_bih + 1024, node_bhh + 1024,
                                           xgbuf, 1024, 1, 512);
  lstm_scan<<<1, 1024, 0, stream>>>(xgbuf, wqN1, scN1, Xc + 256, 8192, 640);

  // --- memory vector: nodes2 @ Wm^T + bm  (nodes2 = Xc[:,256:512]) ---
  gemm_bt<<<dim3(1, 64), 256, 0, stream>>>(Xc + 256, 640, WmB, 256, bm, nullptr,
                                           out1, 128, 1, 256);

  // --- controller LSTM ---
  gemm_bt<<<dim3(8, 64), 256, 0, stream>>>(Xc, 640, cWihB, 640, cbih, cbhh,
                                           xgbuf, 1024, 1, 640);
  lstm_scan<<<1, 1024, 0, stream>>>(xgbuf, wqC, scC, hsC, 8192, 256);

  // --- output layer ---
  gemm_bt<<<dim3(2, 64), 256, 0, stream>>>(hsC, 256, WoB, 256, bo, nullptr,
                                           out0, 256, 1, 256);
}

// Round 9
// 17703.593 us; speedup vs baseline: 1.2442x; 1.2442x over previous
//
#include <hip/hip_runtime.h>

// GraphMemoryNetwork on MI355X — all reference tensors are float32.
// 7 small GEMMs (bf16 MFMA, f32 accum) + 3 sequential LSTM scans of T=8192.
// Scan v5: i8 MFMA matvec. Rows permuted row'=unit*4+gate. 512 threads
// (8 waves); wave owns 128 gate-rows = 8 row-tiles; K=256 = 4 chunks of 64;
// 32 x mfma_i32_16x16x64_i8 per wave per step, A(weights) register-resident,
// B = h i8 replicated in all 16 cols (chunk reduction chained in the acc).
// C/D layout puts the 4 gate preacts of one unit into one lane's 4 regs.
// ROUND-9 FIX: round-8 failed (absmax 8.2e-2) because WmB was sized 16 KB but
// actually needs 64 KB, overlapping scR*/pb* — f2bf_flat(Wm) clobbered the
// permuted biases AFTER bias_perm wrote them, so all 3 xg GEMMs added ~0.05
// garbage biases. scR*/pb* moved to disjoint offsets past scF*.

typedef __attribute__((ext_vector_type(8))) short short8;   // 8 bf16 (4 VGPRs)
typedef __attribute__((ext_vector_type(4))) float f32x4;
typedef __attribute__((ext_vector_type(4))) int i32x4;

#define LOG2E 1.44269504088896340736f

__device__ __forceinline__ float fast_sigmoid(float x) {
  float e = __builtin_amdgcn_exp2f(-x * LOG2E);
  return __builtin_amdgcn_rcpf(1.0f + e);
}
__device__ __forceinline__ float fast_tanh(float x) {
  float e = __builtin_amdgcn_exp2f(x * (2.0f * LOG2E));   // e^{2x}
  return 1.0f - 2.0f * __builtin_amdgcn_rcpf(e + 1.0f);
}

__device__ __forceinline__ unsigned short f2bf(float x) {  // RNE, no NaN inputs
  unsigned int u = __float_as_uint(x);
  u += 0x7FFFu + ((u >> 16) & 1u);
  return (unsigned short)(u >> 16);
}

#if __has_builtin(__builtin_amdgcn_mfma_i32_16x16x64_i8)
#define MFMA_I8(a, b, c) __builtin_amdgcn_mfma_i32_16x16x64_i8((a), (b), (c), 0, 0, 0)
#define MFMA_FENCE()
#else
__device__ __forceinline__ i32x4 mfma_i8_asm(i32x4 a, i32x4 b, i32x4 c) {
  i32x4 d;
  asm volatile("v_mfma_i32_16x16x64_i8 %0, %1, %2, %3"
               : "=v"(d) : "v"(a), "v"(b), "v"(c));
  return d;
}
#define MFMA_I8(a, b, c) mfma_i8_asm((a), (b), (c))
#define MFMA_FENCE() asm volatile("s_nop 7\ns_nop 7" ::: "memory")
#endif

// ---------------------------------------------------------------------------
// GEMM: C[M,N] = A[M,K] * W[N,K]^T + bias0 + bias1.  A,W bf16 row-major
// (ushort). biases f32. 128x128 tile, BK=64, 4 waves (2x2), 16x16x32 bf16
// MFMA, reg-staged LDS.  K % 64 == 0.
// ---------------------------------------------------------------------------
__global__ __launch_bounds__(256) void gemm_bt(
    const unsigned short* __restrict__ A, int lda,
    const unsigned short* __restrict__ W, int ldw,
    const float* __restrict__ bias0,
    const float* __restrict__ bias1,
    void* __restrict__ C, int ldc, int c_f32, int K)
{
  __shared__ unsigned short As[128 * 64];
  __shared__ unsigned short Bs[128 * 64];
  const int tid = threadIdx.x;
  const int lane = tid & 63;
  const int w = tid >> 6;
  const int wm = w >> 1, wn = w & 1;
  const int bm = blockIdx.y * 128, bn = blockIdx.x * 128;

  f32x4 acc[4][4];
#pragma unroll
  for (int m = 0; m < 4; ++m)
#pragma unroll
    for (int n = 0; n < 4; ++n)
      acc[m][n] = (f32x4){0.f, 0.f, 0.f, 0.f};

  for (int k0 = 0; k0 < K; k0 += 64) {
    uint4 va[4], vb[4];
#pragma unroll
    for (int i = 0; i < 4; ++i) {
      int c = i * 256 + tid;                  // 16B chunk id within 128x64 tile
      va[i] = *(const uint4*)(A + (size_t)(bm + (c >> 3)) * lda + k0 + (c & 7) * 8);
      vb[i] = *(const uint4*)(W + (size_t)(bn + (c >> 3)) * ldw + k0 + (c & 7) * 8);
    }
    __syncthreads();                          // prev-iter LDS reads done
#pragma unroll
    for (int i = 0; i < 4; ++i) {
      int c = i * 256 + tid;
      *(uint4*)&As[c * 8] = va[i];
      *(uint4*)&Bs[c * 8] = vb[i];
    }
    __syncthreads();                          // tile ready
#pragma unroll
    for (int ks = 0; ks < 2; ++ks) {
      short8 a[4], b[4];
#pragma unroll
      for (int m = 0; m < 4; ++m)
        a[m] = *(const short8*)&As[(wm * 64 + m * 16 + (lane & 15)) * 64 + ks * 32 + (lane >> 4) * 8];
#pragma unroll
      for (int n = 0; n < 4; ++n)
        b[n] = *(const short8*)&Bs[(wn * 64 + n * 16 + (lane & 15)) * 64 + ks * 32 + (lane >> 4) * 8];
#pragma unroll
      for (int m = 0; m < 4; ++m)
#pragma unroll
        for (int n = 0; n < 4; ++n)
          acc[m][n] = __builtin_amdgcn_mfma_f32_16x16x32_bf16(a[m], b[n], acc[m][n], 0, 0, 0);
    }
  }

  // epilogue: C/D layout col=lane&15, row=(lane>>4)*4+reg
#pragma unroll
  for (int n = 0; n < 4; ++n) {
    int col = bn + wn * 64 + n * 16 + (lane & 15);
    float bsum = 0.f;
    if (bias0) bsum += bias0[col];
    if (bias1) bsum += bias1[col];
#pragma unroll
    for (int m = 0; m < 4; ++m) {
      int rbase = bm + wm * 64 + m * 16 + ((lane >> 4) * 4);
#pragma unroll
      for (int q = 0; q < 4; ++q) {
        float v = acc[m][n][q] + bsum;
        if (c_f32)
          ((float*)C)[(size_t)(rbase + q) * ldc + col] = v;
        else
          ((unsigned short*)C)[(size_t)(rbase + q) * ldc + col] = f2bf(v);
      }
    }
  }
}

// ---------------------------------------------------------------------------
// f32 -> bf16 conversions
// ---------------------------------------------------------------------------
__global__ void f2bf_flat(const float* __restrict__ src,
                          unsigned short* __restrict__ dst, int n4)
{
  int gid = blockIdx.x * 256 + threadIdx.x;
  if (gid >= n4) return;
  f32x4 v = ((const f32x4*)src)[gid];
  ushort4 o;
  o.x = f2bf(v.x); o.y = f2bf(v.y); o.z = f2bf(v.z); o.w = f2bf(v.w);
  ((ushort4*)dst)[gid] = o;
}

// copy f32 [rows, width] (contig) into bf16 [rows, dstLd] column block
__global__ void f2bf_strided(const float* __restrict__ src,
                             unsigned short* __restrict__ dst, int dstLd,
                             int chunkShift, int total)   // chunks of 4 elems
{
  int gid = blockIdx.x * 256 + threadIdx.x;
  if (gid >= total) return;
  int row = gid >> chunkShift;
  int ch = gid & ((1 << chunkShift) - 1);
  f32x4 v = ((const f32x4*)src)[(size_t)gid];
  ushort4 o;
  o.x = f2bf(v.x); o.y = f2bf(v.y); o.z = f2bf(v.z); o.w = f2bf(v.w);
  *(ushort4*)(dst + (size_t)row * dstLd + ch * 4) = o;
}

// f32 [1024,K] -> bf16 [1024,K] with ROW PERMUTATION: dst row' <- src row
// orig(row') = (row'&3)*256 + (row'>>2).  One block per dst row.
__global__ void f2bf_perm(const float* __restrict__ src,
                          unsigned short* __restrict__ dst, int K)
{
  int rowp = blockIdx.x;
  int orig = (rowp & 3) * 256 + (rowp >> 2);
  int t = threadIdx.x;
  if (t * 4 >= K) return;
  f32x4 v = *(const f32x4*)(src + (size_t)orig * K + t * 4);
  ushort4 o;
  o.x = f2bf(v.x); o.y = f2bf(v.y); o.z = f2bf(v.z); o.w = f2bf(v.w);
  *(ushort4*)(dst + (size_t)rowp * K + t * 4) = o;
}

// ---------------------------------------------------------------------------
// Per-row scale of Whh [1024 x 256]: scR[row] = max|w| / 127. One wave/row.
// ---------------------------------------------------------------------------
__global__ void row_scale(const float* __restrict__ Wsrc,
                          float* __restrict__ scR, int nrows)
{
  int row = blockIdx.x * 4 + (threadIdx.x >> 6);
  if (row >= nrows) return;
  int lane = threadIdx.x & 63;
  float mx = 0.f;
#pragma unroll
  for (int i = 0; i < 4; ++i)
    mx = fmaxf(mx, fabsf(Wsrc[(size_t)row * 256 + lane * 4 + i]));
#pragma unroll
  for (int d = 32; d >= 1; d >>= 1) mx = fmaxf(mx, __shfl_xor(mx, d));
  if (lane == 0) scR[row] = mx / 127.f;
}

// scF[row'] = scR[orig(row')] / 127   (dot descale: w_sc * h_sc)
__global__ void scale_fold(const float* __restrict__ scR,
                           float* __restrict__ scF)
{
  int i = blockIdx.x * 256 + threadIdx.x;
  if (i >= 1024) return;
  int orig = (i & 3) * 256 + (i >> 2);
  scF[i] = scR[orig] * (1.f / 127.f);
}

// pb[row'] = bih[orig] + bhh[orig]
__global__ void bias_perm(const float* __restrict__ b1,
                          const float* __restrict__ b2,
                          float* __restrict__ pb)
{
  int i = blockIdx.x * 256 + threadIdx.x;
  if (i >= 1024) return;
  int orig = (i & 3) * 256 + (i >> 2);
  pb[i] = b1[orig] + b2[orig];
}

// ---------------------------------------------------------------------------
// Pack Whh into MFMA A-fragments (i8, quantized by scR).
// Scan thread tid (0..511): w=tid>>6, l=tid&63. Fragment dword index
// idx = rr*16 + c*4 + e  (rr=row-tile 0..7, c=K-chunk 0..3, e=reg 0..3).
// Value = bytes k..k+3 of permuted row  row' = (w*8+rr)*16 + (l&15),
// k = c*64 + (l>>4)*16 + e*4.   apk[tid*128 + idx].
// ---------------------------------------------------------------------------
__global__ void pack_mfma(const float* __restrict__ Wsrc,
                          const float* __restrict__ scR,
                          int* __restrict__ apk)
{
  int gid = blockIdx.x * 256 + threadIdx.x;   // 65536
  int tid = gid >> 7, idx = gid & 127;
  int w = tid >> 6, l = tid & 63;
  int rr = idx >> 4, c = (idx >> 2) & 3, e = idx & 3;
  int rowp = (w * 8 + rr) * 16 + (l & 15);
  int orig = (rowp & 3) * 256 + (rowp >> 2);
  int kb = c * 64 + ((l >> 4) << 4) + e * 4;
  float s = scR[orig];
  float inv = (s > 0.f) ? 1.f / s : 0.f;
  const float* src = Wsrc + (size_t)orig * 256 + kb;
  int packed = 0;
#pragma unroll
  for (int i = 0; i < 4; ++i) {
    int q = __float2int_rn(src[i] * inv);
    q = max(-127, min(127, q));
    packed |= (q & 0xFF) << (8 * i);
  }
  apk[gid] = packed;
}

// ---------------------------------------------------------------------------
// Sequential LSTM scan v5 (i8 MFMA). T steps, 512 threads = 8 waves.
// Wave w owns row-tiles 8w..8w+7 (16 permuted gate-rows each).
// Lane l: A row = l&15, k-group g = l>>4. Lane col cc=l&15 activates
// row-tile rt = cc>>1 (even cc writes). Unit u = (8w+rt)*4 + g.
// ---------------------------------------------------------------------------
__global__ __launch_bounds__(512)
void lstm_scan(
    const float* __restrict__ xg,     // [T][1024] f32, PERMUTED cols (u*4+gate)
    const i32x4* __restrict__ apk,    // packed A fragments
    const float* __restrict__ scF,    // [1024] permuted: w_sc*h_sc per row'
    unsigned short* __restrict__ hs,  // [T][ldh] bf16 output (unit-indexed)
    int T, int ldh)
{
  const int tid = threadIdx.x;
  const int w = tid >> 6;
  const int l = tid & 63;
  const int g = l >> 4;               // k-group
  const int cc = l & 15;              // output column
  const int rt = cc >> 1;             // row-tile this lane activates
  const int u = (w * 8 + rt) * 4 + g; // hidden unit
  const bool active = (cc & 1) == 0;

  // A fragments: 32 x i32x4 per thread
  i32x4 a[8][4];
  {
    const i32x4* ap = apk + (size_t)tid * 32;
#pragma unroll
    for (int rr = 0; rr < 8; ++rr)
#pragma unroll
      for (int c = 0; c < 4; ++c)
        a[rr][c] = ap[rr * 4 + c];
  }
  const f32x4 sc = *(const f32x4*)(scF + u * 4);   // per-gate scales of unit u
  bool msk[8];
#pragma unroll
  for (int i = 0; i < 8; ++i) msk[i] = (rt == i);

  __shared__ __align__(16) char hqb[2][256];  // h as i8 (scale 127), dbuf
  if (tid < 128) ((int*)hqb)[tid] = 0;
  float cst = 0.f;                             // cell state (per active lane)
  const i32x4 zero = (i32x4){0, 0, 0, 0};

  f32x4 xcur = *(const f32x4*)(xg + u * 4);
  __syncthreads();

#define STEP(T_, RB, WB)                                                  \
  {                                                                       \
    f32x4 xnext = *(const f32x4*)(xg + (size_t)((T_) + 1) * 1024 + u * 4);\
    i32x4 b0 = *(const i32x4*)(&hqb[RB][0 * 64 + g * 16]);                \
    i32x4 b1 = *(const i32x4*)(&hqb[RB][1 * 64 + g * 16]);                \
    i32x4 b2 = *(const i32x4*)(&hqb[RB][2 * 64 + g * 16]);                \
    i32x4 b3 = *(const i32x4*)(&hqb[RB][3 * 64 + g * 16]);                \
    i32x4 acc[8];                                                         \
    _Pragma("unroll")                                                     \
    for (int rr = 0; rr < 8; ++rr) {                                      \
      i32x4 d = MFMA_I8(a[rr][0], b0, zero);                              \
      d = MFMA_I8(a[rr][1], b1, d);                                       \
      d = MFMA_I8(a[rr][2], b2, d);                                       \
      d = MFMA_I8(a[rr][3], b3, d);                                       \
      acc[rr] = d;                                                        \
    }                                                                     \
    MFMA_FENCE();                                                         \
    i32x4 sel = acc[0];                                                   \
    _Pragma("unroll")                                                     \
    for (int i = 1; i < 8; ++i) {                                         \
      sel.x = msk[i] ? acc[i].x : sel.x;                                  \
      sel.y = msk[i] ? acc[i].y : sel.y;                                  \
      sel.z = msk[i] ? acc[i].z : sel.z;                                  \
      sel.w = msk[i] ? acc[i].w : sel.w;                                  \
    }                                                                     \
    float pi = fmaf((float)sel.x, sc.x, xcur.x);                          \
    float pf = fmaf((float)sel.y, sc.y, xcur.y);                          \
    float pg = fmaf((float)sel.z, sc.z, xcur.z);                          \
    float po = fmaf((float)sel.w, sc.w, xcur.w);                          \
    float ii = fast_sigmoid(pi);                                          \
    float ff = fast_sigmoid(pf);                                          \
    float gg = fast_tanh(pg);                                             \
    float oo = fast_sigmoid(po);                                          \
    cst = fmaf(ff, cst, ii * gg);                                         \
    float h = oo * fast_tanh(cst);                                        \
    if (active) {                                                         \
      hs[(size_t)(T_) * ldh + u] = f2bf(h);                               \
      int q = __float2int_rn(h * 127.f);                                  \
      q = max(-127, min(127, q));                                         \
      hqb[WB][u] = (char)q;                                               \
    }                                                                     \
    xcur = xnext;                                                         \
    asm volatile("s_waitcnt lgkmcnt(0)" ::: "memory");                    \
    __builtin_amdgcn_s_barrier();                                         \
    asm volatile("" ::: "memory");                                        \
  }

  for (int t = 0; t < T; t += 2) {
    STEP(t, 0, 1);
    STEP(t + 1, 1, 0);
  }
#undef STEP
}

// ---------------------------------------------------------------------------
// pair[n] = [nodes[e0[n]] | nodes[e1[n]]]  (bf16, 16B chunks)
// ---------------------------------------------------------------------------
__global__ void gather_pair(const unsigned short* __restrict__ nodes,
                            const int* __restrict__ edges,
                            unsigned short* __restrict__ pair)
{
  int gid = blockIdx.x * 256 + threadIdx.x;   // over 8192*64 chunks
  int row = gid >> 6;
  int ch = gid & 63;
  int side = ch >> 5;
  int k = ch & 31;
  int src = edges[row * 2 + side];
  uint4 v = ((const uint4*)(nodes + (size_t)src * 256))[k];
  ((uint4*)(pair + (size_t)row * 512))[ch] = v;
}

// ---------------------------------------------------------------------------
extern "C" void kernel_launch(void* const* d_in, const int* in_sizes, int n_in,
                              void* d_out, int out_size, void* d_ws, size_t ws_size,
                              hipStream_t stream)
{
  const float* inputs   = (const float*)d_in[0];
  const int*   edges    = (const int*)d_in[1];
  const float* memory   = (const float*)d_in[2];
  const float* Wi       = (const float*)d_in[3];
  const float* bi       = (const float*)d_in[4];
  const float* Wo       = (const float*)d_in[5];
  const float* bo       = (const float*)d_in[6];
  const float* edge_W   = (const float*)d_in[7];
  const float* edge_b   = (const float*)d_in[8];
  const float* node_Wih = (const float*)d_in[9];
  const float* node_Whh = (const float*)d_in[10];
  const float* node_bih = (const float*)d_in[11];
  const float* node_bhh = (const float*)d_in[12];
  const float* Wm       = (const float*)d_in[13];
  const float* bm       = (const float*)d_in[14];
  const float* cWih     = (const float*)d_in[15];
  const float* cWhh     = (const float*)d_in[16];
  const float* cbih     = (const float*)d_in[17];
  const float* cbhh     = (const float*)d_in[18];

  char* ws = (char*)d_ws;
  float*          xgbuf  = (float*)(ws + 0);                    // [8192,1024] f32
  unsigned short* Xbf    = (unsigned short*)(ws + 33554432);    // [8192,512]
  unsigned short* Xc     = (unsigned short*)(ws + 41943040);    // [8192,640]
  unsigned short* nodes0 = (unsigned short*)(ws + 52428800);    // [8192,256]
  unsigned short* nodesA = (unsigned short*)(ws + 56623104);    // [8192,256]
  unsigned short* PAIR   = (unsigned short*)(ws + 60817408);    // [8192,512]
  unsigned short* hsC    = (unsigned short*)(ws + 69206016);    // [8192,256]
  unsigned short* WiB    = (unsigned short*)(ws + 73400320);    // 131072 B
  unsigned short* WoB    = (unsigned short*)(ws + 73531392);    // 131072 B
  unsigned short* eWB    = (unsigned short*)(ws + 73662464);    // 524288 B
  unsigned short* nWihB  = (unsigned short*)(ws + 74186752);    // 2097152 B
  unsigned short* WmB    = (unsigned short*)(ws + 76283904);    // 65536 B (FULL)
  unsigned short* cWihB  = (unsigned short*)(ws + 76349440);    // 1310720 B
  int*            apkN0  = (int*)(ws + 77660160);               // 262144 B
  int*            apkN1  = (int*)(ws + 77922304);               // 262144 B
  int*            apkC   = (int*)(ws + 78184448);               // 262144 B
  float*          scF0   = (float*)(ws + 78446592);             // [1024]
  float*          scF1   = (float*)(ws + 78450688);             // [1024]
  float*          scFC   = (float*)(ws + 78454784);             // [1024]
  float*          scR0   = (float*)(ws + 78458880);             // [1024]  (moved)
  float*          scR1   = (float*)(ws + 78462976);             // [1024]  (moved)
  float*          scR2   = (float*)(ws + 78467072);             // [1024]  (moved)
  float*          pb0    = (float*)(ws + 78471168);             // [1024]  (moved)
  float*          pb1    = (float*)(ws + 78475264);             // [1024]  (moved)
  float*          pbC    = (float*)(ws + 78479360);             // [1024]  (moved)

  float* out0 = (float*)d_out;                // out     [8192,256] f32
  float* out1 = out0 + 8192 * 256;            // memvec  [8192,128] f32

  // --- prep: scales, MFMA weight packs, permuted Wih/biases, bf16 weights ---
  row_scale<<<256, 256, 0, stream>>>(node_Whh, scR0, 1024);
  row_scale<<<256, 256, 0, stream>>>(node_Whh + 1024 * 256, scR1, 1024);
  row_scale<<<256, 256, 0, stream>>>(cWhh, scR2, 1024);
  pack_mfma<<<256, 256, 0, stream>>>(node_Whh, scR0, apkN0);
  pack_mfma<<<256, 256, 0, stream>>>(node_Whh + 1024 * 256, scR1, apkN1);
  pack_mfma<<<256, 256, 0, stream>>>(cWhh, scR2, apkC);
  scale_fold<<<4, 256, 0, stream>>>(scR0, scF0);
  scale_fold<<<4, 256, 0, stream>>>(scR1, scF1);
  scale_fold<<<4, 256, 0, stream>>>(scR2, scFC);
  bias_perm<<<4, 256, 0, stream>>>(node_bih, node_bhh, pb0);
  bias_perm<<<4, 256, 0, stream>>>(node_bih + 1024, node_bhh + 1024, pb1);
  bias_perm<<<4, 256, 0, stream>>>(cbih, cbhh, pbC);
  f2bf_flat<<<64, 256, 0, stream>>>(Wi, WiB, 16384);
  f2bf_flat<<<64, 256, 0, stream>>>(Wo, WoB, 16384);
  f2bf_flat<<<256, 256, 0, stream>>>(edge_W, eWB, 65536);
  f2bf_flat<<<32, 256, 0, stream>>>(Wm, WmB, 8192);
  f2bf_perm<<<1024, 256, 0, stream>>>(node_Wih, nWihB, 512);
  f2bf_perm<<<1024, 256, 0, stream>>>(node_Wih + 1024 * 512, nWihB + 1024 * 512, 512);
  f2bf_perm<<<1024, 256, 0, stream>>>(cWih, cWihB, 640);

  // --- static column blocks (inputs, memory) as bf16 ---
  f2bf_strided<<<2048, 256, 0, stream>>>(inputs, Xbf, 512, 6, 8192 * 64);
  f2bf_strided<<<2048, 256, 0, stream>>>(inputs, Xc, 640, 6, 8192 * 64);
  f2bf_strided<<<1024, 256, 0, stream>>>(memory, Xc + 512, 640, 5, 8192 * 32);

  // --- input layer: nodes0 = inputs @ Wi^T + bi ---
  gemm_bt<<<dim3(2, 64), 256, 0, stream>>>(Xbf, 512, WiB, 256, bi, nullptr,
                                           nodes0, 256, 0, 256);

  // --- relation r = 0 ---
  gather_pair<<<2048, 256, 0, stream>>>(nodes0, edges, PAIR);
  gemm_bt<<<dim3(2, 64), 256, 0, stream>>>(PAIR, 512, eWB, 512, edge_b, nullptr,
                                           Xbf + 256, 512, 0, 512);
  gemm_bt<<<dim3(8, 64), 256, 0, stream>>>(Xbf, 512, nWihB, 512, pb0, nullptr,
                                           xgbuf, 1024, 1, 512);
  lstm_scan<<<1, 512, 0, stream>>>(xgbuf, (const i32x4*)apkN0, scF0, nodesA, 8192, 256);

  // --- relation r = 1 (LSTM writes straight into Xc[:,256:512]) ---
  gather_pair<<<2048, 256, 0, stream>>>(nodesA, edges, PAIR);
  gemm_bt<<<dim3(2, 64), 256, 0, stream>>>(PAIR, 512, eWB + 256 * 512, 512,
                                           edge_b + 256, nullptr, Xbf + 256, 512, 0, 512);
  gemm_bt<<<dim3(8, 64), 256, 0, stream>>>(Xbf, 512, nWihB + 1024 * 512, 512,
                                           pb1, nullptr, xgbuf, 1024, 1, 512);
  lstm_scan<<<1, 512, 0, stream>>>(xgbuf, (const i32x4*)apkN1, scF1, Xc + 256, 8192, 640);

  // --- memory vector: nodes2 @ Wm^T + bm  (nodes2 = Xc[:,256:512]) ---
  gemm_bt<<<dim3(1, 64), 256, 0, stream>>>(Xc + 256, 640, WmB, 256, bm, nullptr,
                                           out1, 128, 1, 256);

  // --- controller LSTM ---
  gemm_bt<<<dim3(8, 64), 256, 0, stream>>>(Xc, 640, cWihB, 640, pbC, nullptr,
                                           xgbuf, 1024, 1, 640);
  lstm_scan<<<1, 512, 0, stream>>>(xgbuf, (const i32x4*)apkC, scFC, hsC, 8192, 256);

  // --- output layer ---
  gemm_bt<<<dim3(2, 64), 256, 0, stream>>>(hsC, 256, WoB, 256, bo, nullptr,
                                           out0, 256, 1, 256);
}